// Round 3
// baseline (321.836 us; speedup 1.0000x reference)
//
#include <hip/hip_runtime.h>
#include <hip/hip_cooperative_groups.h>

namespace cg = cooperative_groups;

constexpr int Nn = 64, Tt = 512, Vv = 17, Oo = 64;
constexpr int TV  = Tt * Vv;      // 8704
constexpr int CTV = 3 * TV;       // 26112
constexpr int NT  = Nn * Tt;      // 32768
constexpr float EPSf = 1e-5f;
constexpr int GB   = 512;         // cooperative grid (2 blocks/CU on 256 CUs)
constexpr int CHPN = GB / Nn;     // 8 chunks per n
constexpr int TCH  = Tt / CHPN;   // 64 t-rows per chunk
constexpr int BTV  = TCH * Vv;    // 1088 tv per block

// exact floor(v/17) for v < ~60000 (17*61681 = 2^20+1)
__device__ inline int div17(int v) { return (int)(((unsigned)v * 61681u) >> 20); }

__device__ inline double wred(double v) {
#pragma unroll
  for (int o = 32; o > 0; o >>= 1) v += __shfl_down(v, o, 64);
  return v;
}

__global__ void __launch_bounds__(256, 2) fused(
    const float* __restrict__ x,
    const float* __restrict__ w1, const float* __restrict__ b1,
    const float* __restrict__ w2, const float* __restrict__ b2,
    const float* __restrict__ cw, const float* __restrict__ cb,
    const float* __restrict__ cg_, const float* __restrict__ cbeta,
    const float* __restrict__ PA, const float* __restrict__ alpha,
    const float* __restrict__ c2w, const float* __restrict__ c2b,
    const float* __restrict__ bng, const float* __restrict__ bnb,
    const float* __restrict__ pw, const float* __restrict__ pb,
    const float* __restrict__ pg, const float* __restrict__ pbeta,
    float* __restrict__ out,
    double* __restrict__ spart, float* __restrict__ a3part,
    float* __restrict__ Amat, double* __restrict__ ypart,
    double* __restrict__ ysum)
{
  __shared__ float smem[2 * 3 * BTV];   // 6528 f: phase B l1/l2 union, phase D/F xs|ys
  __shared__ float As[289];
  __shared__ float coefs[512];
  __shared__ double dred[4][18];
  __shared__ float sfl[2];

  cg::grid_group grid = cg::this_grid();
  const int tid = threadIdx.x, bid = blockIdx.x;
  const int n = bid >> 3, ch = bid & 7;       // CHPN = 8
  const int t0 = ch * TCH;

  // uniform folded weights: u = w^T * convT_w, d = b . convT_w
  float u1[3], u2[3];
#pragma unroll
  for (int k = 0; k < 3; ++k) {
    float s1 = 0.f, s2 = 0.f;
#pragma unroll
    for (int c = 0; c < 3; ++c) { s1 += cw[c] * w1[c * 3 + k]; s2 += cw[c] * w2[c * 3 + k]; }
    u1[k] = s1; u2[k] = s2;
  }
  float d1 = 0.f, d2 = 0.f;
#pragma unroll
  for (int c = 0; c < 3; ++c) { d1 += b1[c] * cw[c]; d2 += b2[c] * cw[c]; }
  const float bb = cb[0];

  // ---------- Phase A: s-statistic partials (4 lanes per (n,t) row, v-split) ----------
  {
    int g = bid * 256 + tid, row = g >> 2, p = g & 3;
    int v0 = (p == 0) ? 0 : (1 + p * 4);
    int vc = (p == 0) ? 5 : 4;
    const float* xp = x + ((size_t)row * Vv + v0) * 3;   // x as (N,T,V,C)
    float A = 0.f, G = 0.f, Q1 = 0.f, Q2 = 0.f;
    for (int k = 0; k < vc; ++k) {
      float x0 = xp[k * 3], x1 = xp[k * 3 + 1], x2 = xp[k * 3 + 2];
      float va1 = fmaf(x0, u1[0], fmaf(x1, u1[1], fmaf(x2, u1[2], d1)));
      float va2 = fmaf(x0, u2[0], fmaf(x1, u2[1], fmaf(x2, u2[2], d2)));
      float gg = bb - va2;
      A += va1; G += gg;
      Q1 = fmaf(va1, va1, Q1); Q2 = fmaf(gg, gg, Q2);
    }
    // row sums across the 4-lane group for the cross term
    float Ar = A + __shfl_xor(A, 1, 64); Ar += __shfl_xor(Ar, 2, 64);
    float Gr = G + __shfl_xor(G, 1, 64); Gr += __shfl_xor(Gr, 2, 64);
    double st[5] = { (double)A, (double)G, (double)Q1, (double)Q2,
                     (p == 0) ? (double)Ar * (double)Gr : 0.0 };
    int wv = tid >> 6;
#pragma unroll
    for (int s = 0; s < 5; ++s) { double r = wred(st[s]); if ((tid & 63) == 0) dred[wv][s] = r; }
    __syncthreads();
    if (tid < 5)
      spart[(size_t)bid * 5 + tid] = dred[0][tid] + dred[1][tid] + dred[2][tid] + dred[3][tid];
  }
  grid.sync();

  // ---------- Phase B: a3 partials (per-block redundant s-stat reduce -> scale/c0) ----------
  {
    double v5[5];
#pragma unroll
    for (int s = 0; s < 5; ++s)
      v5[s] = spart[(size_t)tid * 5 + s] + spart[(size_t)(tid + 256) * 5 + s];
    int wv = tid >> 6;
#pragma unroll
    for (int s = 0; s < 5; ++s) { double r = wred(v5[s]); if ((tid & 63) == 0) dred[wv][s] = r; }
    __syncthreads();
    if (tid == 0) {
      double S[5];
#pragma unroll
      for (int s = 0; s < 5; ++s) S[s] = dred[0][s] + dred[1][s] + dred[2][s] + dred[3][s];
      double cnt = (double)Nn * Tt * Vv * Vv;
      double mean = ((double)Vv * (S[0] + S[1])) / cnt;
      double m2   = ((double)Vv * (S[2] + S[3]) + 2.0 * S[4]) / cnt;
      double var  = m2 - mean * mean;
      double scale = (double)cg_[0] / sqrt(var + (double)EPSf);
      double shift = (double)cbeta[0] + scale * ((double)bb - mean);
      sfl[0] = (float)scale; sfl[1] = (float)(shift - scale * (double)bb);
    }
    __syncthreads();
    float scale = sfl[0], c0 = sfl[1];
    float* l1 = smem; float* l2 = smem + 1152;
    int tend = t0 + TCH; if (tend > Tt - 1) tend = Tt - 1;
    int nload = tend - t0 + 1, total = nload * Vv;
    for (int idx = tid; idx < total; idx += 256) {
      int r = div17(idx), vv = idx - r * 17;
      const float* xp = x + ((size_t)((n * Tt + t0 + r) * Vv + vv)) * 3;
      float x0 = xp[0], x1 = xp[1], x2 = xp[2];
      float va1 = fmaf(x0, u1[0], fmaf(x1, u1[1], fmaf(x2, u1[2], d1)));
      float va2 = fmaf(x0, u2[0], fmaf(x1, u2[1], fmaf(x2, u2[2], d2)));
      l1[idx] = va1; l2[idx] = bb - va2;   // s_raw = l1[j] + l2[i]
    }
    __syncthreads();
    for (int e = tid; e < 289; e += 256) {
      int i = div17(e), j = e - i * 17;
      float prev = fmaxf(fmaf(scale, l1[j] + l2[i], c0), 0.f), acc = 0.f;
      for (int r = 1; r < nload; ++r) {
        float cur = fmaxf(fmaf(scale, l1[r * 17 + j] + l2[r * 17 + i], c0), 0.f);
        acc += fabsf(cur - prev); prev = cur;
      }
      a3part[(size_t)e * GB + bid] = acc;
    }
  }
  grid.sync();

  // ---------- Phase C: A-matrix (one entry per block, bid < 289) ----------
  if (bid < 289) {
    double v = (double)a3part[(size_t)bid * GB + tid]
             + (double)a3part[(size_t)bid * GB + tid + 256];
    double r = wred(v);
    int wv = tid >> 6;
    if ((tid & 63) == 0) dred[wv][0] = r;
    __syncthreads();
    if (tid == 0) {
      float tot = (float)((dred[0][0] + dred[1][0] + dred[2][0] + dred[3][0]) * (1.0 / Nn));
      Amat[bid] = fmaf(alpha[bid], tot, PA[bid]);
    }
  }
  grid.sync();

  // ---------- Phase D: stage x chunk, compute y chunk into LDS, y/x moment partials ----------
  {
    for (int e = tid; e < 289; e += 256) As[e] = Amat[e];
    float* xs = smem; float* ys = smem + 3 * BTV;
    const float* xb = x + (size_t)n * CTV + (size_t)t0 * Vv;  // x viewed as (N,C,T,V)
#pragma unroll
    for (int c = 0; c < 3; ++c)
      for (int i4 = tid; i4 < BTV / 4; i4 += 256)
        *(float4*)&xs[c * BTV + i4 * 4] = *(const float4*)(xb + (size_t)c * TV + i4 * 4);
    __syncthreads();
    float st[18];
#pragma unroll
    for (int s = 0; s < 18; ++s) st[s] = 0.f;
#pragma unroll
    for (int k = 0; k < 5; ++k) {
      int e = k * 256 + tid;
      if (e < BTV) {
        int tr = div17(e), v = e - tr * 17;
        const float* r0 = &xs[tr * 17];
        const float* r1 = &xs[BTV + tr * 17];
        const float* r2 = &xs[2 * BTV + tr * 17];
        float y0 = 0.f, y1 = 0.f, y2 = 0.f;
#pragma unroll
        for (int u = 0; u < 17; ++u) {
          float a = As[u * 17 + v];
          y0 = fmaf(r0[u], a, y0); y1 = fmaf(r1[u], a, y1); y2 = fmaf(r2[u], a, y2);
        }
        ys[e] = y0; ys[BTV + e] = y1; ys[2 * BTV + e] = y2;
        float x0 = xs[e], x1 = xs[BTV + e], x2 = xs[2 * BTV + e];
        st[0] += y0; st[1] += y1; st[2] += y2;
        st[3] = fmaf(y0, y0, st[3]); st[4] = fmaf(y0, y1, st[4]); st[5] = fmaf(y0, y2, st[5]);
        st[6] = fmaf(y1, y1, st[6]); st[7] = fmaf(y1, y2, st[7]); st[8] = fmaf(y2, y2, st[8]);
        st[9] += x0; st[10] += x1; st[11] += x2;
        st[12] = fmaf(x0, x0, st[12]); st[13] = fmaf(x0, x1, st[13]); st[14] = fmaf(x0, x2, st[14]);
        st[15] = fmaf(x1, x1, st[15]); st[16] = fmaf(x1, x2, st[16]); st[17] = fmaf(x2, x2, st[17]);
      }
    }
    int wv = tid >> 6;
#pragma unroll
    for (int s = 0; s < 18; ++s) { double r = wred((double)st[s]); if ((tid & 63) == 0) dred[wv][s] = r; }
    __syncthreads();
    if (tid < 18)
      ypart[(size_t)bid * 18 + tid] = dred[0][tid] + dred[1][tid] + dred[2][tid] + dred[3][tid];
  }
  grid.sync();

  // ---------- Phase E: reduce moment partials (one stat per block, bid < 18) ----------
  if (bid < 18) {
    double v = ypart[(size_t)tid * 18 + bid] + ypart[(size_t)(tid + 256) * 18 + bid];
    double r = wred(v);
    int wv = tid >> 6;
    if ((tid & 63) == 0) dred[wv][0] = r;
    __syncthreads();
    if (tid == 0) ysum[bid] = dred[0][0] + dred[1][0] + dred[2][0] + dred[3][0];
  }
  grid.sync();

  // ---------- Phase F: per-block coef, then fused output from persistent LDS xs/ys ----------
  {
    if (tid < 64) {
      int o = tid;
      const double cnt = (double)Nn * Tt * Vv;
      double my0 = ysum[0] / cnt, my1 = ysum[1] / cnt, my2 = ysum[2] / cnt;
      double e00 = ysum[3] / cnt, e01 = ysum[4] / cnt, e02 = ysum[5] / cnt;
      double e11 = ysum[6] / cnt, e12 = ysum[7] / cnt, e22 = ysum[8] / cnt;
      double mx0 = ysum[9] / cnt, mx1 = ysum[10] / cnt, mx2 = ysum[11] / cnt;
      double f00 = ysum[12] / cnt, f01 = ysum[13] / cnt, f02 = ysum[14] / cnt;
      double f11 = ysum[15] / cnt, f12 = ysum[16] / cnt, f22 = ysum[17] / cnt;
      double w0 = c2w[o * 3], w1_ = c2w[o * 3 + 1], w2_ = c2w[o * 3 + 2], bz = c2b[o];
      double wm = w0 * my0 + w1_ * my1 + w2_ * my2, mz = wm + bz;
      double Ez2 = w0 * w0 * e00 + 2 * w0 * w1_ * e01 + 2 * w0 * w2_ * e02
                 + w1_ * w1_ * e11 + 2 * w1_ * w2_ * e12 + w2_ * w2_ * e22
                 + 2 * bz * wm + bz * bz;
      double sz = (double)bng[o] / sqrt(Ez2 - mz * mz + (double)EPSf);
      double q0 = pw[o * 3], q1 = pw[o * 3 + 1], q2 = pw[o * 3 + 2], bp = pb[o];
      double qm = q0 * mx0 + q1 * mx1 + q2 * mx2, mp = qm + bp;
      double Ep2 = q0 * q0 * f00 + 2 * q0 * q1 * f01 + 2 * q0 * q2 * f02
                 + q1 * q1 * f11 + 2 * q1 * q2 * f12 + q2 * q2 * f22
                 + 2 * bp * qm + bp * bp;
      double sp = (double)pg[o] / sqrt(Ep2 - mp * mp + (double)EPSf);
      coefs[o * 8 + 0] = (float)(sz * w0); coefs[o * 8 + 1] = (float)(sz * w1_); coefs[o * 8 + 2] = (float)(sz * w2_);
      coefs[o * 8 + 3] = (float)(sp * q0); coefs[o * 8 + 4] = (float)(sp * q1); coefs[o * 8 + 5] = (float)(sp * q2);
      coefs[o * 8 + 6] = (float)(sz * (bz - mz) + (double)bnb[o] + sp * (bp - mp) + (double)pbeta[o]);
      coefs[o * 8 + 7] = 0.f;
    }
    __syncthreads();
    const float* xs = smem; const float* ys = smem + 3 * BTV;
    float* ob = out + (size_t)n * ((size_t)Oo * TV) + (size_t)t0 * Vv;
#pragma unroll 2
    for (int k = 0; k < 68; ++k) {           // 68*256 = 64 o * 272 float4
      int idx = k * 256 + tid;
      int o = div17(idx >> 4);               // idx / 272, 272 = 16*17
      int q = idx - o * 272, tq = q * 4;
      float4 y0 = *(const float4*)&ys[tq];
      float4 y1 = *(const float4*)&ys[BTV + tq];
      float4 y2 = *(const float4*)&ys[2 * BTV + tq];
      float4 xq0 = *(const float4*)&xs[tq];
      float4 xq1 = *(const float4*)&xs[BTV + tq];
      float4 xq2 = *(const float4*)&xs[2 * BTV + tq];
      float a0 = coefs[o * 8 + 0], a1 = coefs[o * 8 + 1], a2 = coefs[o * 8 + 2];
      float p0 = coefs[o * 8 + 3], p1 = coefs[o * 8 + 4], p2 = coefs[o * 8 + 5];
      float be = coefs[o * 8 + 6];
      float4 r;
      r.x = fmaxf(fmaf(a0, y0.x, fmaf(a1, y1.x, fmaf(a2, y2.x, fmaf(p0, xq0.x, fmaf(p1, xq1.x, fmaf(p2, xq2.x, be)))))), 0.f);
      r.y = fmaxf(fmaf(a0, y0.y, fmaf(a1, y1.y, fmaf(a2, y2.y, fmaf(p0, xq0.y, fmaf(p1, xq1.y, fmaf(p2, xq2.y, be)))))), 0.f);
      r.z = fmaxf(fmaf(a0, y0.z, fmaf(a1, y1.z, fmaf(a2, y2.z, fmaf(p0, xq0.z, fmaf(p1, xq1.z, fmaf(p2, xq2.z, be)))))), 0.f);
      r.w = fmaxf(fmaf(a0, y0.w, fmaf(a1, y1.w, fmaf(a2, y2.w, fmaf(p0, xq0.w, fmaf(p1, xq1.w, fmaf(p2, xq2.w, be)))))), 0.f);
      *(float4*)(ob + (size_t)o * TV + tq) = r;
    }
  }
}

extern "C" void kernel_launch(void* const* d_in, const int* in_sizes, int n_in,
                              void* d_out, int out_size, void* d_ws, size_t ws_size,
                              hipStream_t stream)
{
  (void)in_sizes; (void)n_in; (void)out_size; (void)ws_size;
  const float* x     = (const float*)d_in[0];
  const float* w1    = (const float*)d_in[1];
  const float* b1    = (const float*)d_in[2];
  const float* w2    = (const float*)d_in[3];
  const float* b2    = (const float*)d_in[4];
  const float* cw    = (const float*)d_in[5];
  const float* cb    = (const float*)d_in[6];
  const float* cg_   = (const float*)d_in[7];
  const float* cbeta = (const float*)d_in[8];
  const float* PA    = (const float*)d_in[9];
  const float* alpha = (const float*)d_in[10];
  const float* c2w   = (const float*)d_in[11];
  const float* c2b   = (const float*)d_in[12];
  const float* bng   = (const float*)d_in[13];
  const float* bnb   = (const float*)d_in[14];
  const float* pw    = (const float*)d_in[15];
  const float* pb    = (const float*)d_in[16];
  const float* pg    = (const float*)d_in[17];
  const float* pbeta = (const float*)d_in[18];
  float* out = (float*)d_out;

  char* ws = (char*)d_ws;
  double* spart  = (double*)(ws + 0);        // 512*5  doubles = 20480 B
  float*  a3part = (float*)(ws + 20480);     // 289*512 floats = 591872 B -> 612352
  float*  Amat   = (float*)(ws + 612352);    // 289 floats -> pad to 613888
  double* ypart  = (double*)(ws + 613888);   // 512*18 doubles = 73728 B -> 687616
  double* ysum   = (double*)(ws + 687616);   // 18 doubles

  void* args[] = {
    (void*)&x, (void*)&w1, (void*)&b1, (void*)&w2, (void*)&b2,
    (void*)&cw, (void*)&cb, (void*)&cg_, (void*)&cbeta,
    (void*)&PA, (void*)&alpha, (void*)&c2w, (void*)&c2b,
    (void*)&bng, (void*)&bnb, (void*)&pw, (void*)&pb, (void*)&pg, (void*)&pbeta,
    (void*)&out, (void*)&spart, (void*)&a3part, (void*)&Amat, (void*)&ypart, (void*)&ysum
  };
  hipLaunchCooperativeKernel((const void*)fused, dim3(GB), dim3(256), args, 0, stream);
}

// Round 4
// 87.644 us; speedup vs baseline: 3.6721x; 3.6721x over previous
//
#include <hip/hip_runtime.h>

constexpr int Nn = 64, Tt = 512, Vv = 17, Oo = 64;
constexpr int TV  = Tt * Vv;      // 8704
constexpr int CTV = 3 * TV;       // 26112
constexpr int NT  = Nn * Tt;      // 32768
constexpr float EPSf = 1e-5f;
constexpr int GB1 = 512;          // K1 blocks
constexpr int RPB = 64;           // rows per K1 block
constexpr int NU  = 289;          // ordered (u,u') units
constexpr int GE  = 1792;         // padded gram entries (6*289+51 = 1785 used)
constexpr int TCH = 256;          // K2 t-chunk
constexpr int K2B = 128;          // K2 blocks
constexpr int BTV = 1088;         // 64*17 floats per c-plane chunk

// exact floor(v/17) for v < ~60000
__device__ inline int div17(int v) { return (int)(((unsigned)v * 61681u) >> 20); }

__device__ inline double wred(double v) {
#pragma unroll
  for (int o = 32; o > 0; o >>= 1) v += __shfl_down(v, o, 64);
  return v;
}

// ---------------------------------------------------------------------------
// K1: s-stat partials (5 f64/block) + x-Gram partials (1785 f32/block).
// Gram: M[cc'][u,u'] = sum_{n,t} xr[n,c,t,u]*xr[n,c',t,u'] (xr = raw (N,C,T,V) view)
__global__ void __launch_bounds__(256) k1(
    const float* __restrict__ x,
    const float* __restrict__ w1, const float* __restrict__ b1,
    const float* __restrict__ w2, const float* __restrict__ b2,
    const float* __restrict__ cw, const float* __restrict__ cb,
    double* __restrict__ spart, float* __restrict__ gpart)
{
  __shared__ float xsA[RPB * 51];   // 64 original (n,t) rows, contiguous chunk
  __shared__ float xsB[3 * BTV];    // 3 c-plane segments of the xr view
  __shared__ double dred[4][5];
  const int tid = threadIdx.x, bid = blockIdx.x;
  const int n = bid >> 3, ch = bid & 7;

  // stage xsA: flat [bid*3264, +3264)
  {
    const float4* src = (const float4*)(x + (size_t)bid * 3264);
    float4* dst = (float4*)xsA;
    for (int i = tid; i < 816; i += 256) dst[i] = src[i];
  }
  // stage xsB: 3 segments n*CTV + c*TV + ch*1088
#pragma unroll
  for (int c = 0; c < 3; ++c) {
    const float4* src = (const float4*)(x + (size_t)n * CTV + (size_t)c * TV + ch * BTV);
    float4* dst = (float4*)(xsB + c * BTV);
    for (int i = tid; i < 272; i += 256) dst[i] = src[i];
  }
  __syncthreads();

  // folded weights
  float u1[3], u2[3];
#pragma unroll
  for (int k = 0; k < 3; ++k) {
    float s1 = 0.f, s2 = 0.f;
#pragma unroll
    for (int c = 0; c < 3; ++c) { s1 += cw[c] * w1[c * 3 + k]; s2 += cw[c] * w2[c * 3 + k]; }
    u1[k] = s1; u2[k] = s2;
  }
  float d1 = 0.f, d2 = 0.f;
#pragma unroll
  for (int c = 0; c < 3; ++c) { d1 += b1[c] * cw[c]; d2 += b2[c] * cw[c]; }
  const float bb = cb[0];

  // s-stats: thread < 64 owns one original row
  double st[5] = {0, 0, 0, 0, 0};
  if (tid < RPB) {
    const float* rp = xsA + tid * 51;
    float A = 0.f, G = 0.f, Q1 = 0.f, Q2 = 0.f;
#pragma unroll
    for (int v = 0; v < 17; ++v) {
      float x0 = rp[v * 3], x1 = rp[v * 3 + 1], x2 = rp[v * 3 + 2];
      float va1 = fmaf(x0, u1[0], fmaf(x1, u1[1], fmaf(x2, u1[2], d1)));
      float va2 = fmaf(x0, u2[0], fmaf(x1, u2[1], fmaf(x2, u2[2], d2)));
      float g = bb - va2;
      A += va1; G += g;
      Q1 = fmaf(va1, va1, Q1); Q2 = fmaf(g, g, Q2);
    }
    st[0] = A; st[1] = G; st[2] = Q1; st[3] = Q2; st[4] = (double)A * (double)G;
  }
  {
    int wv = tid >> 6;
#pragma unroll
    for (int s = 0; s < 5; ++s) { double r = wred(st[s]); if ((tid & 63) == 0) dred[wv][s] = r; }
  }

  // Gram units (ordered (u,u')): 6 cc' pairs each
  float* gp = gpart + (size_t)bid * GE;
#pragma unroll
  for (int pass = 0; pass < 2; ++pass) {
    int k = tid + pass * 256;
    if (k < NU) {
      int u = div17(k), up = k - u * 17;
      float h0 = 0, h1 = 0, h2 = 0, h3 = 0, h4 = 0, h5 = 0;
      for (int t = 0; t < RPB; ++t) {
        int ro = t * 17;
        float a0 = xsB[ro + u],        a1 = xsB[BTV + ro + u],  a2 = xsB[2 * BTV + ro + u];
        float b0 = xsB[ro + up],       b1 = xsB[BTV + ro + up], b2 = xsB[2 * BTV + ro + up];
        h0 = fmaf(a0, b0, h0); h1 = fmaf(a0, b1, h1); h2 = fmaf(a0, b2, h2);
        h3 = fmaf(a1, b1, h3); h4 = fmaf(a1, b2, h4); h5 = fmaf(a2, b2, h5);
      }
      gp[0 * NU + k] = h0; gp[1 * NU + k] = h1; gp[2 * NU + k] = h2;
      gp[3 * NU + k] = h3; gp[4 * NU + k] = h4; gp[5 * NU + k] = h5;
    }
  }
  // means m[c][u]
  if (tid < 51) {
    int c = div17(tid), u = tid - c * 17;
    float m = 0.f;
    for (int t = 0; t < RPB; ++t) m += xsB[c * BTV + t * 17 + u];
    gp[6 * NU + tid] = m;
  }
  if (tid < GE - 1785) gp[1785 + tid] = 0.f;   // pad

  __syncthreads();
  if (tid < 5)
    spart[(size_t)bid * 5 + tid] = dred[0][tid] + dred[1][tid] + dred[2][tid] + dred[3][tid];
}

// ---------------------------------------------------------------------------
// K2: a3 partials (per-block redundant s-stat reduce) + Gram finalize (14 entries/block)
__global__ void __launch_bounds__(256) k2(
    const float* __restrict__ x, const double* __restrict__ spart,
    const float* __restrict__ gpart,
    const float* __restrict__ w1, const float* __restrict__ b1,
    const float* __restrict__ w2, const float* __restrict__ b2,
    const float* __restrict__ cw, const float* __restrict__ cb,
    const float* __restrict__ cg_, const float* __restrict__ cbeta,
    float* __restrict__ a3part, double* __restrict__ gramF)
{
  __shared__ float l1[(TCH + 1) * Vv];   // 4369
  __shared__ float l2[(TCH + 1) * Vv];
  __shared__ double dred[4][14];
  __shared__ float sfl[2];
  const int tid = threadIdx.x;
  const int jb = blockIdx.y * 2 + blockIdx.x;
  const int wv = tid >> 6;

  // (a) reduce s-stat partials (512 rows)
  {
    double v5[5];
#pragma unroll
    for (int s = 0; s < 5; ++s)
      v5[s] = spart[(size_t)tid * 5 + s] + spart[(size_t)(tid + 256) * 5 + s];
#pragma unroll
    for (int s = 0; s < 5; ++s) { double r = wred(v5[s]); if ((tid & 63) == 0) dred[wv][s] = r; }
  }
  __syncthreads();
  if (tid == 0) {
    double S[5];
#pragma unroll
    for (int s = 0; s < 5; ++s) S[s] = dred[0][s] + dred[1][s] + dred[2][s] + dred[3][s];
    double cnt = (double)Nn * Tt * Vv * Vv;
    double mean = ((double)Vv * (S[0] + S[1])) / cnt;
    double m2   = ((double)Vv * (S[2] + S[3]) + 2.0 * S[4]) / cnt;
    double var  = m2 - mean * mean;
    double scale = (double)cg_[0] / sqrt(var + (double)EPSf);
    double shift = (double)cbeta[0] + scale * ((double)cb[0] - mean);
    sfl[0] = (float)scale; sfl[1] = (float)(shift - scale * (double)cb[0]);
  }
  __syncthreads();

  // (b) Gram finalize: entries [jb*14, jb*14+14)
  {
    int e0 = jb * 14;
    const float* g1 = gpart + (size_t)tid * GE + e0;
    const float* g2 = gpart + (size_t)(tid + 256) * GE + e0;
    double gv[14];
#pragma unroll
    for (int k = 0; k < 14; ++k) gv[k] = (double)g1[k] + (double)g2[k];
#pragma unroll
    for (int k = 0; k < 14; ++k) { double r = wred(gv[k]); if ((tid & 63) == 0) dred[wv][k] = r; }
    __syncthreads();
    if (tid < 14)
      gramF[e0 + tid] = dred[0][tid] + dred[1][tid] + dred[2][tid] + dred[3][tid];
  }

  // (c) stage a1/g into LDS
  float u1[3], u2[3];
#pragma unroll
  for (int k = 0; k < 3; ++k) {
    float s1 = 0.f, s2 = 0.f;
#pragma unroll
    for (int c = 0; c < 3; ++c) { s1 += cw[c] * w1[c * 3 + k]; s2 += cw[c] * w2[c * 3 + k]; }
    u1[k] = s1; u2[k] = s2;
  }
  float d1 = 0.f, d2 = 0.f;
#pragma unroll
  for (int c = 0; c < 3; ++c) { d1 += b1[c] * cw[c]; d2 += b2[c] * cw[c]; }
  const float bb = cb[0];

  const int n = blockIdx.y, t0 = blockIdx.x * TCH;
  int tend = t0 + TCH; if (tend > Tt - 1) tend = Tt - 1;
  const int nload = tend - t0 + 1, total = nload * 17;
  for (int idx = tid; idx < total; idx += 256) {
    int r = div17(idx), vv = idx - r * 17;
    const float* xp = x + ((size_t)((n * Tt + t0 + r) * 17 + vv)) * 3;
    float x0 = xp[0], x1 = xp[1], x2 = xp[2];
    float va1 = fmaf(x0, u1[0], fmaf(x1, u1[1], fmaf(x2, u1[2], d1)));
    float va2 = fmaf(x0, u2[0], fmaf(x1, u2[1], fmaf(x2, u2[2], d2)));
    l1[idx] = va1; l2[idx] = bb - va2;    // s_raw = l1[j] + l2[i]
  }
  __syncthreads();

  // (d) a3 accumulation
  {
    float scale = sfl[0], c0 = sfl[1];
    for (int e = tid; e < 289; e += 256) {
      int i = div17(e), j = e - i * 17;
      float prev = fmaxf(fmaf(scale, l1[j] + l2[i], c0), 0.f), acc = 0.f;
      for (int r = 1; r < nload; ++r) {
        float cur = fmaxf(fmaf(scale, l1[r * 17 + j] + l2[r * 17 + i], c0), 0.f);
        acc += fabsf(cur - prev); prev = cur;
      }
      a3part[(size_t)jb * 289 + e] = acc;
    }
  }
}

// ---------------------------------------------------------------------------
// K3: A (redundant reduce) -> moments from Gram -> coefs -> fused output
__global__ void __launch_bounds__(256, 2) k3(
    const float* __restrict__ x,
    const float* __restrict__ PA, const float* __restrict__ alpha,
    const float* __restrict__ a3part, const double* __restrict__ gramF,
    const float* __restrict__ c2w, const float* __restrict__ c2b,
    const float* __restrict__ bng, const float* __restrict__ bnb,
    const float* __restrict__ pw, const float* __restrict__ pb,
    const float* __restrict__ pg, const float* __restrict__ pbeta,
    float* __restrict__ out)
{
  __shared__ float xs[3 * BTV], ys[3 * BTV];
  __shared__ float As[NU], Bh[NU], rsA[17], coefs[512];
  __shared__ double gs[GE], mom[18];
  const int tid = threadIdx.x, bid = blockIdx.x;
  const int n = bid >> 3, ch = bid & 7;
  const int t0c = ch * BTV;

  // phase 1: load gram + reduce a3 -> A
  for (int e = tid; e < GE; e += 256) gs[e] = gramF[e];
  for (int e = tid; e < NU; e += 256) {
    float acc = 0.f;
#pragma unroll 4
    for (int j = 0; j < K2B; ++j) acc += a3part[(size_t)j * NU + e];
    As[e] = fmaf(alpha[e], acc * (1.0f / Nn), PA[e]);
  }
  __syncthreads();

  // phase 2: B = A A^T (ordered units), row sums of A
  for (int k = tid; k < NU; k += 256) {
    int u = div17(k), up = k - u * 17;
    float s = 0.f;
#pragma unroll
    for (int v = 0; v < 17; ++v) s = fmaf(As[u * 17 + v], As[up * 17 + v], s);
    Bh[k] = s;
  }
  if (tid < 17) {
    float s = 0.f;
#pragma unroll
    for (int v = 0; v < 17; ++v) s += As[tid * 17 + v];
    rsA[tid] = s;
  }
  __syncthreads();

  // phase 3: 18 moments
  if (tid < 6) {                       // Eyy_p * cnt
    double s = 0.0;
    for (int k = 0; k < NU; ++k) s += gs[tid * NU + k] * (double)Bh[k];
    mom[3 + tid] = s;
  } else if (tid < 12) {               // Exx_p * cnt (diagonal units)
    int p = tid - 6; double s = 0.0;
#pragma unroll
    for (int u = 0; u < 17; ++u) s += gs[p * NU + u * 18];
    mom[12 + p] = s;
  } else if (tid < 15) {               // sum y_c
    int c = tid - 12; double s = 0.0;
#pragma unroll
    for (int u = 0; u < 17; ++u) s += gs[6 * NU + c * 17 + u] * (double)rsA[u];
    mom[c] = s;
  } else if (tid < 18) {               // sum x_c
    int c = tid - 15; double s = 0.0;
#pragma unroll
    for (int u = 0; u < 17; ++u) s += gs[6 * NU + c * 17 + u];
    mom[9 + c] = s;
  }
  __syncthreads();

  // phase 4: stage xs + per-o coefs
#pragma unroll
  for (int c = 0; c < 3; ++c) {
    const float4* src = (const float4*)(x + (size_t)n * CTV + (size_t)c * TV + t0c);
    float4* dst = (float4*)(xs + c * BTV);
    for (int i = tid; i < 272; i += 256) dst[i] = src[i];
  }
  if (tid < 64) {
    int o = tid;
    const double cnt = (double)Nn * Tt * Vv;
    double my0 = mom[0] / cnt, my1 = mom[1] / cnt, my2 = mom[2] / cnt;
    double e00 = mom[3] / cnt, e01 = mom[4] / cnt, e02 = mom[5] / cnt;
    double e11 = mom[6] / cnt, e12 = mom[7] / cnt, e22 = mom[8] / cnt;
    double mx0 = mom[9] / cnt, mx1 = mom[10] / cnt, mx2 = mom[11] / cnt;
    double f00 = mom[12] / cnt, f01 = mom[13] / cnt, f02 = mom[14] / cnt;
    double f11 = mom[15] / cnt, f12 = mom[16] / cnt, f22 = mom[17] / cnt;
    double w0 = c2w[o * 3], w1_ = c2w[o * 3 + 1], w2_ = c2w[o * 3 + 2], bz = c2b[o];
    double wm = w0 * my0 + w1_ * my1 + w2_ * my2, mz = wm + bz;
    double Ez2 = w0 * w0 * e00 + 2 * w0 * w1_ * e01 + 2 * w0 * w2_ * e02
               + w1_ * w1_ * e11 + 2 * w1_ * w2_ * e12 + w2_ * w2_ * e22
               + 2 * bz * wm + bz * bz;
    double sz = (double)bng[o] / sqrt(Ez2 - mz * mz + (double)EPSf);
    double q0 = pw[o * 3], q1 = pw[o * 3 + 1], q2 = pw[o * 3 + 2], bp = pb[o];
    double qm = q0 * mx0 + q1 * mx1 + q2 * mx2, mp = qm + bp;
    double Ep2 = q0 * q0 * f00 + 2 * q0 * q1 * f01 + 2 * q0 * q2 * f02
               + q1 * q1 * f11 + 2 * q1 * q2 * f12 + q2 * q2 * f22
               + 2 * bp * qm + bp * bp;
    double sp = (double)pg[o] / sqrt(Ep2 - mp * mp + (double)EPSf);
    coefs[o * 8 + 0] = (float)(sz * w0); coefs[o * 8 + 1] = (float)(sz * w1_); coefs[o * 8 + 2] = (float)(sz * w2_);
    coefs[o * 8 + 3] = (float)(sp * q0); coefs[o * 8 + 4] = (float)(sp * q1); coefs[o * 8 + 5] = (float)(sp * q2);
    coefs[o * 8 + 6] = (float)(sz * (bz - mz) + (double)bnb[o] + sp * (bp - mp) + (double)pbeta[o]);
    coefs[o * 8 + 7] = 0.f;
  }
  __syncthreads();

  // phase 5: y chunk into LDS
#pragma unroll
  for (int k = 0; k < 5; ++k) {
    int e = k * 256 + tid;
    if (e < BTV) {
      int tr = div17(e), v = e - tr * 17;
      float y0 = 0.f, y1 = 0.f, y2 = 0.f;
#pragma unroll
      for (int u = 0; u < 17; ++u) {
        float a = As[u * 17 + v];
        y0 = fmaf(xs[tr * 17 + u], a, y0);
        y1 = fmaf(xs[BTV + tr * 17 + u], a, y1);
        y2 = fmaf(xs[2 * BTV + tr * 17 + u], a, y2);
      }
      ys[e] = y0; ys[BTV + e] = y1; ys[2 * BTV + e] = y2;
    }
  }
  __syncthreads();

  // phase 6: fused output
  float* ob = out + (size_t)n * ((size_t)Oo * TV) + t0c;
#pragma unroll 2
  for (int k = 0; k < 68; ++k) {          // 68*256 = 64 o * 272 float4
    int idx = k * 256 + tid;
    int o = div17(idx >> 4);
    int q = idx - o * 272, tq = q * 4;
    float4 y0 = *(const float4*)&ys[tq];
    float4 y1 = *(const float4*)&ys[BTV + tq];
    float4 y2 = *(const float4*)&ys[2 * BTV + tq];
    float4 x0 = *(const float4*)&xs[tq];
    float4 x1 = *(const float4*)&xs[BTV + tq];
    float4 x2 = *(const float4*)&xs[2 * BTV + tq];
    float a0 = coefs[o * 8 + 0], a1 = coefs[o * 8 + 1], a2 = coefs[o * 8 + 2];
    float p0 = coefs[o * 8 + 3], p1 = coefs[o * 8 + 4], p2 = coefs[o * 8 + 5];
    float be = coefs[o * 8 + 6];
    float4 r;
    r.x = fmaxf(fmaf(a0, y0.x, fmaf(a1, y1.x, fmaf(a2, y2.x, fmaf(p0, x0.x, fmaf(p1, x1.x, fmaf(p2, x2.x, be)))))), 0.f);
    r.y = fmaxf(fmaf(a0, y0.y, fmaf(a1, y1.y, fmaf(a2, y2.y, fmaf(p0, x0.y, fmaf(p1, x1.y, fmaf(p2, x2.y, be)))))), 0.f);
    r.z = fmaxf(fmaf(a0, y0.z, fmaf(a1, y1.z, fmaf(a2, y2.z, fmaf(p0, x0.z, fmaf(p1, x1.z, fmaf(p2, x2.z, be)))))), 0.f);
    r.w = fmaxf(fmaf(a0, y0.w, fmaf(a1, y1.w, fmaf(a2, y2.w, fmaf(p0, x0.w, fmaf(p1, x1.w, fmaf(p2, x2.w, be)))))), 0.f);
    *(float4*)(ob + (size_t)o * TV + tq) = r;
  }
}

extern "C" void kernel_launch(void* const* d_in, const int* in_sizes, int n_in,
                              void* d_out, int out_size, void* d_ws, size_t ws_size,
                              hipStream_t stream)
{
  (void)in_sizes; (void)n_in; (void)out_size; (void)ws_size;
  const float* x     = (const float*)d_in[0];
  const float* w1    = (const float*)d_in[1];
  const float* b1    = (const float*)d_in[2];
  const float* w2    = (const float*)d_in[3];
  const float* b2    = (const float*)d_in[4];
  const float* cw    = (const float*)d_in[5];
  const float* cb    = (const float*)d_in[6];
  const float* cg_   = (const float*)d_in[7];
  const float* cbeta = (const float*)d_in[8];
  const float* PA    = (const float*)d_in[9];
  const float* alpha = (const float*)d_in[10];
  const float* c2w   = (const float*)d_in[11];
  const float* c2b   = (const float*)d_in[12];
  const float* bng   = (const float*)d_in[13];
  const float* bnb   = (const float*)d_in[14];
  const float* pw    = (const float*)d_in[15];
  const float* pb    = (const float*)d_in[16];
  const float* pg    = (const float*)d_in[17];
  const float* pbeta = (const float*)d_in[18];
  float* out = (float*)d_out;

  char* ws = (char*)d_ws;
  double* spart  = (double*)(ws + 0);          // 512*5*8   = 20480
  float*  gpart  = (float*)(ws + 20480);       // 512*1792*4 = 3670016 -> ends 3690496
  float*  a3part = (float*)(ws + 3690496);     // 128*289*4  = 147968  -> ends 3838464
  double* gramF  = (double*)(ws + 3838464);    // 1792*8     = 14336   -> ends 3852800

  hipLaunchKernelGGL(k1, dim3(GB1), dim3(256), 0, stream,
                     x, w1, b1, w2, b2, cw, cb, spart, gpart);
  hipLaunchKernelGGL(k2, dim3(2, Nn), dim3(256), 0, stream,
                     x, spart, gpart, w1, b1, w2, b2, cw, cb, cg_, cbeta, a3part, gramF);
  hipLaunchKernelGGL(k3, dim3(512), dim3(256), 0, stream,
                     x, PA, alpha, a3part, gramF, c2w, c2b, bng, bnb,
                     pw, pb, pg, pbeta, out);
}